// Round 5
// baseline (476.580 us; speedup 1.0000x reference)
//
#include <hip/hip_runtime.h>
#include <stdint.h>

#define N_EDGES 500000
#define N_NODES 100000
#define PREP_NG 2     // node-groups per wave in prep_p
#define TBINS 1280    // dist table bins, step 1/32, range [0,40); lerp lookup

typedef __attribute__((ext_vector_type(8))) short short8;
typedef __attribute__((ext_vector_type(4))) float floatx4;
typedef __attribute__((ext_vector_type(2))) float f32x2;

// RNE (one-time prep only)
__device__ __forceinline__ uint16_t f2bf(float f) {
  union { float f; uint32_t u; } cv; cv.f = f;
  uint32_t u = cv.u;
  return (uint16_t)((u + 0x7FFFu + ((u >> 16) & 1u)) >> 16);
}
// truncating pack of two f32 -> bf16x2 (single v_perm_b32)
__device__ __forceinline__ uint32_t pk2bf(float lo, float hi) {
  return __builtin_amdgcn_perm(__float_as_uint(hi), __float_as_uint(lo), 0x07060302u);
}
__device__ __forceinline__ uint16_t bftrunc(float f) {
  return (uint16_t)(__float_as_uint(f) >> 16);
}
__device__ __forceinline__ float lrelu(float v) { return fmaxf(v, 0.001f * v); }

// unpack bf16x2 word -> f32x2 {lo, hi}
__device__ __forceinline__ f32x2 unpk2(uint32_t u) {
  return (f32x2){ __uint_as_float(u << 16), __uint_as_float(u & 0xFFFF0000u) };
}
// h = lrelu(Pa+Pb + lerp(T0,T1,w)) for one bf16x2 word; pk-fp32 math
__device__ __forceinline__ uint32_t comp2(uint32_t a, uint32_t b, uint32_t t0, uint32_t t1,
                                          f32x2 w2) {
  f32x2 p  = unpk2(a) + unpk2(b);
  f32x2 v0 = unpk2(t0), v1 = unpk2(t1);
  f32x2 r  = p + (v0 + w2 * (v1 - v0));
  f32x2 rl = r * 0.001f;
  return pk2bf(fmaxf(r.x, rl.x), fmaxf(r.y, rl.y));
}
__device__ __forceinline__ floatx4 lrelu4(floatx4 v) {
  floatx4 w = v * 0.001f;
  v.x = fmaxf(v.x, w.x); v.y = fmaxf(v.y, w.y);
  v.z = fmaxf(v.z, w.z); v.w = fmaxf(v.w, w.w);
  return v;
}

// ============ prep0: W1/W2 + W0[0:256] -> MFMA-fragment order (bf16); BE0; pos copy ============
__global__ void prep0_kernel(const float* __restrict__ W0, const float* __restrict__ b0,
                             const float* __restrict__ W1, const float* __restrict__ W2,
                             const float* __restrict__ bemb,
                             uint16_t* __restrict__ w0ab, uint16_t* __restrict__ w1f,
                             uint16_t* __restrict__ w2f, float* __restrict__ be0f,
                             const float* __restrict__ pos, float* __restrict__ out, int npos) {
  int id = blockIdx.x * 256 + threadIdx.x;
  if (id < 32768) {                       // w0ab: ks(4) x ntt(16) x lane(64) x j(8)
    int f = id;
    int j = f & 7, lane = (f >> 3) & 63, ntt = (f >> 9) & 15, ks = f >> 13;
    int k = ks * 32 + (lane >> 4) * 8 + j;
    int row = (ntt < 8) ? k : (128 + k);            // ntt<8 -> P_a cols, else P_b cols
    int col = (ntt & 7) * 16 + (lane & 15);
    w0ab[f] = f2bf(W0[row * 128 + col]);
  } else if (id < 49152) {                // w1f
    int f = id - 32768;
    int j = f & 7, lane = (f >> 3) & 63, nt = (f >> 9) & 7, ks = f >> 12;
    int k = ks * 32 + (lane >> 4) * 8 + j;
    w1f[f] = f2bf(W1[k * 128 + nt * 16 + (lane & 15)]);
  } else if (id < 65536) {                // w2f
    int f = id - 49152;
    int j = f & 7, lane = (f >> 3) & 63, nt = (f >> 9) & 7, ks = f >> 12;
    int k = ks * 32 + (lane >> 4) * 8 + j;
    w2f[f] = f2bf(W2[k * 128 + nt * 16 + (lane & 15)]);
  } else if (id < 66048) {                // BE0[t][n] = bond_emb[t]@W0[256:320] + b0 (f32)
    int t = id - 65536; int ty = t >> 7, n = t & 127;
    float s = b0[n];
    for (int kk = 0; kk < 64; ++kk) s += bemb[ty * 64 + kk] * W0[(256 + kk) * 128 + n];
    be0f[t] = s;
  } else if (id - 66048 < npos) {         // pos -> out
    out[id - 66048] = pos[id - 66048];
  }
}

// ============ prep_tp: merged T-table + P_a/P_b precompute (independent halves) ============
__global__ __attribute__((amdgpu_flat_work_group_size(256, 256)))
void prep_tp_kernel(const float* __restrict__ W0, const float* __restrict__ be0f,
                    uint16_t* __restrict__ T,
                    const float* __restrict__ nemb, const uint16_t* __restrict__ w0ab,
                    uint16_t* __restrict__ Pa, uint16_t* __restrict__ Pb) {
  __shared__ __align__(16) uint16_t aLds[4 * PREP_NG * 16 * 136];
  __shared__ __align__(16) uint16_t sS[4][16][72];   // per-wave store staging (72 = 64+8 pad)
  __shared__ float rbf[64];
  const int tid = threadIdx.x;

  if (blockIdx.x < TBINS) {
    // ---- T-table half: one block per bin ----
    int b = blockIdx.x;
    float dist = (float)b * (1.0f / 32.0f);
    const float delta = 20.0f / 62.0f;
    const float coeff = -0.5f / (delta * delta);
    if (tid < 64) {
      float v;
      if (tid < 63) { float d = dist - (float)tid * delta; v = __expf(coeff * d * d); }
      else v = (dist >= 20.0f) ? 1.0f : 0.0f;
      rbf[tid] = v;
    }
    __syncthreads();
    float sum = 0.0f;
    for (int k = 0; k < 64; ++k) sum += rbf[k];
    float rs = 1.0f / sum;
    for (int o = tid; o < 512; o += 256) {
      int ty = o >> 7, n = o & 127;
      float s = be0f[ty * 128 + n];
      for (int k = 0; k < 64; ++k) s += rbf[k] * rs * W0[(320 + k) * 128 + n];
      T[((size_t)(ty * TBINS + b)) * 128 + n] = f2bf(s);
    }
    return;
  }

  // ---- P half ----
  const int pblk = blockIdx.x - TBINS;
  const int lane = tid & 63;
  const int wave = tid >> 6;
  const int n15 = lane & 15;
  const int quad = lane >> 4;
  uint16_t* myA = aLds + wave * (PREP_NG * 16 * 136);
  const int base = pblk * (64 * PREP_NG) + wave * (16 * PREP_NG);

  {
    const int le = lane >> 2, sub = lane & 3;
#pragma unroll
    for (int it = 0; it < PREP_NG; ++it) {
      int r = base + it * 16 + le; if (r >= N_NODES) r = N_NODES - 1;
      const float4* src = (const float4*)(nemb + (size_t)r * 128);
#pragma unroll
      for (int g = 0; g < 4; ++g) {
        float4 a = src[sub * 8 + g * 2], b = src[sub * 8 + g * 2 + 1];
        uint4 pk;
        pk.x = pk2bf(a.x, a.y); pk.y = pk2bf(a.z, a.w);
        pk.z = pk2bf(b.x, b.y); pk.w = pk2bf(b.z, b.w);
        *(uint4*)(myA + (it * 16 + le) * 136 + sub * 32 + g * 8) = pk;
      }
    }
  }

  const short8* wfv = (const short8*)w0ab + lane;
  const int srow = lane >> 2, sch = lane & 3;   // store read-back mapping
#pragma unroll
  for (int q = 0; q < 4; ++q) {
    short8 bfr[16];
#pragma unroll
    for (int ks = 0; ks < 4; ++ks)
#pragma unroll
      for (int nq = 0; nq < 4; ++nq)
        bfr[ks * 4 + nq] = wfv[(ks * 16 + q * 4 + nq) * 64];
    uint16_t* dst = (q < 2) ? Pa : Pb;
    const int cbase = (q & 1) * 64;
#pragma unroll
    for (int it = 0; it < PREP_NG; ++it) {
      floatx4 acc[4];
#pragma unroll
      for (int nq = 0; nq < 4; ++nq) acc[nq] = (floatx4){0.f, 0.f, 0.f, 0.f};
#pragma unroll
      for (int ks = 0; ks < 4; ++ks) {
        short8 a = *(const short8*)(myA + (it * 16 + n15) * 136 + ks * 32 + quad * 8);
#pragma unroll
        for (int nq = 0; nq < 4; ++nq)
          acc[nq] = __builtin_amdgcn_mfma_f32_16x16x32_bf16(a, bfr[ks * 4 + nq], acc[nq], 0, 0, 0);
      }
      // stage MFMA-layout acc into LDS, read back row-major, store dwordx4
#pragma unroll
      for (int nq = 0; nq < 4; ++nq)
#pragma unroll
        for (int r = 0; r < 4; ++r)
          sS[wave][quad * 4 + r][nq * 16 + n15] = bftrunc(acc[nq][r]);
      int grow = base + it * 16 + srow;
      if (grow < N_NODES) {
        uint16_t* drow = dst + (size_t)grow * 128 + cbase;
#pragma unroll
        for (int h = 0; h < 2; ++h)
          *(uint4*)(drow + (h * 4 + sch) * 8) =
              *(const uint4*)&sS[wave][srow][(h * 4 + sch) * 8];
      }
    }
  }
}

// ---- phase 1 for one 16-edge group: loads grouped BEFORE compute so the wave
// keeps ~16 gather instructions (256 cache lines) in flight. ----
__device__ __forceinline__ void phase1(
    int ge0, int gr0, int lane,
    const float* __restrict__ x, const int* __restrict__ bidx,
    const int* __restrict__ btyp,
    const uint16_t* __restrict__ Pa, const uint16_t* __restrict__ Pb,
    const uint16_t* __restrict__ Tt,
    uint16_t* __restrict__ hA, float (*u_lds)[3], int (*ij_lds)[2]) {
  const int le = lane >> 2, sub = lane & 3;   // 4 lanes per edge
  const int gr = gr0 + le;
  const int ge = ge0 + le;
  const bool valid = ge < N_EDGES;
  int vi = 0, vj = 0, bt = 0;
  if (valid) {
    int2 ij = *(const int2*)(bidx + 2 * ge);
    vi = ij.x; vj = ij.y;
    bt = btyp[ge];
  }
  // issue Pa/Pb gathers first (depend only on bidx)
  const uint4* pa = (const uint4*)(Pa + (size_t)vi * 128 + sub * 32);
  const uint4* pb = (const uint4*)(Pb + (size_t)vj * 128 + sub * 32);
  uint4 A[4], B[4];
#pragma unroll
  for (int g = 0; g < 4; ++g) A[g] = pa[g];
#pragma unroll
  for (int g = 0; g < 4; ++g) B[g] = pb[g];
  // x chain -> dist -> T addresses
  float dx, dy, dz;
  if (valid) {
    float3 xi = *(const float3*)(x + 3 * vi);
    float3 xj = *(const float3*)(x + 3 * vj);
    dx = xi.x - xj.x; dy = xi.y - xj.y; dz = xi.z - xj.z;
  } else { dx = 1.0f; dy = 0.0f; dz = 0.0f; }
  float dist = sqrtf(dx * dx + dy * dy + dz * dz);
  float rinv = 1.0f / dist;
  if (sub == 0) {
    u_lds[gr][0] = dx * rinv; u_lds[gr][1] = dy * rinv; u_lds[gr][2] = dz * rinv;
    ij_lds[gr][0] = vi; ij_lds[gr][1] = vj;
  }
  float fb = fminf(dist, 39.5f) * 32.0f;
  int bi = (int)fb;
  float w = fb - (float)bi;
  f32x2 w2 = {w, w};
  const uint16_t* trow = Tt + ((size_t)(bt * TBINS + bi)) * 128 + sub * 32;
  const uint4* t0p = (const uint4*)trow;
  const uint4* t1p = (const uint4*)(trow + 128);
  uint4 T0[4], T1[4];
#pragma unroll
  for (int g = 0; g < 4; ++g) T0[g] = t0p[g];
#pragma unroll
  for (int g = 0; g < 4; ++g) T1[g] = t1p[g];
  // compute after all loads issued
#pragma unroll
  for (int g = 0; g < 4; ++g) {
    uint4 pk;
    pk.x = comp2(A[g].x, B[g].x, T0[g].x, T1[g].x, w2);
    pk.y = comp2(A[g].y, B[g].y, T0[g].y, T1[g].y, w2);
    pk.z = comp2(A[g].z, B[g].z, T0[g].z, T1[g].z, w2);
    pk.w = comp2(A[g].w, B[g].w, T0[g].w, T1[g].w, w2);
    *(uint4*)(hA + le * 136 + sub * 32 + g * 8) = pk;
  }
}

// GEMM with B-fragments read straight from global (w1f/w2f are 32KB each and
// read by every block -> permanently L1/L2-resident; re-reads add no MISSES).
__device__ __forceinline__ void gemm_g(const uint16_t* __restrict__ wf, const uint16_t* aRow,
                                       int lane, floatx4* acc) {
  short8 a[4];
#pragma unroll
  for (int ks = 0; ks < 4; ++ks) a[ks] = *(const short8*)(aRow + ks * 32);
  const short8* wv = (const short8*)wf + lane;
#pragma unroll
  for (int ks = 0; ks < 4; ++ks)
#pragma unroll
    for (int nt = 0; nt < 8; ++nt)
      acc[nt] = __builtin_amdgcn_mfma_f32_16x16x32_bf16(a[ks], wv[(ks * 8 + nt) * 64], acc[nt], 0, 0, 0);
}

// epilogue 1: +b1, LN, lrelu -> hA (pk-fp32 vector math)
__device__ __forceinline__ void epilogue1(floatx4* acc, uint16_t* hA, int n15, int quad,
                                          const float* __restrict__ b1,
                                          const float* __restrict__ ln1w,
                                          const float* __restrict__ ln1b) {
  float bv[8], wv[8], bb[8];
#pragma unroll
  for (int nt = 0; nt < 8; ++nt) {
    int col = nt * 16 + n15;
    bv[nt] = b1[col]; wv[nt] = ln1w[col]; bb[nt] = ln1b[col];
  }
  floatx4 s4 = {0.f, 0.f, 0.f, 0.f}, q4 = {0.f, 0.f, 0.f, 0.f};
#pragma unroll
  for (int nt = 0; nt < 8; ++nt) { floatx4 v = acc[nt] + bv[nt]; s4 += v; q4 += v * v; }
#pragma unroll
  for (int m = 1; m <= 8; m <<= 1) {
#pragma unroll
    for (int c = 0; c < 4; ++c) { s4[c] += __shfl_xor(s4[c], m); q4[c] += __shfl_xor(q4[c], m); }
  }
  floatx4 mean = s4 * (1.0f / 128.0f);
  floatx4 var = q4 * (1.0f / 128.0f) - mean * mean;
  floatx4 rstd;
  rstd.x = rsqrtf(var.x + 1e-5f); rstd.y = rsqrtf(var.y + 1e-5f);
  rstd.z = rsqrtf(var.z + 1e-5f); rstd.w = rsqrtf(var.w + 1e-5f);
#pragma unroll
  for (int nt = 0; nt < 8; ++nt) {
    floatx4 v = acc[nt] + bv[nt];
    floatx4 vn = lrelu4((v - mean) * (rstd * wv[nt]) + bb[nt]);
#pragma unroll
    for (int r = 0; r < 4; ++r)
      hA[(quad * 4 + r) * 136 + nt * 16 + n15] = bftrunc(vn[r]);
  }
}

// epilogue 2: +b2, LN, lrelu, force = h@Wo + bo, scatter atomics
__device__ __forceinline__ void epilogue2(floatx4* acc, int n15, int quad, int edge0, int gr0,
                                          const float (*u_lds)[3], const int (*ij_lds)[2],
                                          const float* __restrict__ b2,
                                          const float* __restrict__ ln2w,
                                          const float* __restrict__ ln2b,
                                          const float* __restrict__ Wo,
                                          const float* __restrict__ bo,
                                          float* __restrict__ out) {
  float bv[8], wv[8], bb[8], wo0[8], wo1[8];
#pragma unroll
  for (int nt = 0; nt < 8; ++nt) {
    int col = nt * 16 + n15;
    bv[nt] = b2[col]; wv[nt] = ln2w[col]; bb[nt] = ln2b[col];
    wo0[nt] = Wo[2 * col]; wo1[nt] = Wo[2 * col + 1];
  }
  floatx4 s4 = {0.f, 0.f, 0.f, 0.f}, q4 = {0.f, 0.f, 0.f, 0.f};
#pragma unroll
  for (int nt = 0; nt < 8; ++nt) { floatx4 v = acc[nt] + bv[nt]; s4 += v; q4 += v * v; }
#pragma unroll
  for (int m = 1; m <= 8; m <<= 1) {
#pragma unroll
    for (int c = 0; c < 4; ++c) { s4[c] += __shfl_xor(s4[c], m); q4[c] += __shfl_xor(q4[c], m); }
  }
  floatx4 mean = s4 * (1.0f / 128.0f);
  floatx4 var = q4 * (1.0f / 128.0f) - mean * mean;
  floatx4 rstd;
  rstd.x = rsqrtf(var.x + 1e-5f); rstd.y = rsqrtf(var.y + 1e-5f);
  rstd.z = rsqrtf(var.z + 1e-5f); rstd.w = rsqrtf(var.w + 1e-5f);
  floatx4 f0 = {0.f, 0.f, 0.f, 0.f}, f1 = {0.f, 0.f, 0.f, 0.f};
#pragma unroll
  for (int nt = 0; nt < 8; ++nt) {
    floatx4 v = acc[nt] + bv[nt];
    floatx4 vn = lrelu4((v - mean) * (rstd * wv[nt]) + bb[nt]);
    f0 += vn * wo0[nt];
    f1 += vn * wo1[nt];
  }
#pragma unroll
  for (int m = 1; m <= 8; m <<= 1) {
#pragma unroll
    for (int c = 0; c < 4; ++c) { f0[c] += __shfl_xor(f0[c], m); f1[c] += __shfl_xor(f1[c], m); }
  }
  if (n15 < 4) {
    int gr = gr0 + quad * 4 + n15;
    int ge2 = edge0 + quad * 4 + n15;
    if (ge2 < N_EDGES) {
      float F0 = (n15 == 0) ? f0.x : (n15 == 1) ? f0.y : (n15 == 2) ? f0.z : f0.w;
      float F1 = (n15 == 0) ? f1.x : (n15 == 1) ? f1.y : (n15 == 2) ? f1.z : f1.w;
      F0 += bo[0]; F1 += bo[1];
      float ux = u_lds[gr][0], uy = u_lds[gr][1], uz = u_lds[gr][2];
      int ii = ij_lds[gr][0], jj = ij_lds[gr][1];
      float c0 = 0.5f * F0;          // STEP * force0, along +u
      float c1 = -0.5f * F1;         // STEP * force1, along -u
      atomicAdd(out + 3 * ii,     c0 * ux);
      atomicAdd(out + 3 * ii + 1, c0 * uy);
      atomicAdd(out + 3 * ii + 2, c0 * uz);
      atomicAdd(out + 3 * jj,     c1 * ux);
      atomicAdd(out + 3 * jj + 1, c1 * uy);
      atomicAdd(out + 3 * jj + 2, c1 * uz);
    }
  }
}

// ============ main: 128 edges/block, 4 waves, 32 edges/wave (2 groups, 1 acc) ============
// All LDS wave-private -> zero barriers. Two 16-edge groups per wave give ~2x the
// outstanding gather misses per wave; gemms run sequentially per group so only ONE
// acc[8] (32 AGPR) is ever live -> no spills (R4 lesson). waves_per_eu(3) = 170-reg
// budget so both groups' gather loads can be hoisted in flight together.
__global__ __attribute__((amdgpu_flat_work_group_size(256, 256), amdgpu_waves_per_eu(3)))
void bond_mlp_kernel(const float* __restrict__ x,
                     const int* __restrict__ bidx, const int* __restrict__ btyp,
                     const uint16_t* __restrict__ Pa, const uint16_t* __restrict__ Pb,
                     const uint16_t* __restrict__ Tt, const uint16_t* __restrict__ w1f,
                     const uint16_t* __restrict__ w2f,
                     const float* __restrict__ b1, const float* __restrict__ ln1w,
                     const float* __restrict__ ln1b,
                     const float* __restrict__ b2, const float* __restrict__ ln2w,
                     const float* __restrict__ ln2b,
                     const float* __restrict__ Wo, const float* __restrict__ bo,
                     float* __restrict__ out) {
  __shared__ __align__(16) uint16_t hA_all[8 * 16 * 136];   // 4 waves x 2 groups
  __shared__ float u_lds[128][3];
  __shared__ int ij_lds[128][2];

  const int tid = threadIdx.x;
  const int lane = tid & 63;
  const int wave = tid >> 6;
  const int n15 = lane & 15;
  const int quad = lane >> 4;

  uint16_t* hA0 = hA_all + (wave * 2 + 0) * (16 * 136);
  uint16_t* hA1 = hA_all + (wave * 2 + 1) * (16 * 136);

  const int e0 = blockIdx.x * 128 + wave * 32;
  const int r0 = wave * 32;

  phase1(e0,      r0,      lane, x, bidx, btyp, Pa, Pb, Tt, hA0, u_lds, ij_lds);
  phase1(e0 + 16, r0 + 16, lane, x, bidx, btyp, Pa, Pb, Tt, hA1, u_lds, ij_lds);
  // no barrier: hA/u_lds/ij_lds are wave-private; compiler inserts waits

  const uint16_t* aRow0 = hA0 + n15 * 136 + quad * 8;
  const uint16_t* aRow1 = hA1 + n15 * 136 + quad * 8;

  floatx4 acc[8];

#pragma unroll
  for (int nt = 0; nt < 8; ++nt) acc[nt] = (floatx4){0.f, 0.f, 0.f, 0.f};
  gemm_g(w1f, aRow0, lane, acc);
  epilogue1(acc, hA0, n15, quad, b1, ln1w, ln1b);

#pragma unroll
  for (int nt = 0; nt < 8; ++nt) acc[nt] = (floatx4){0.f, 0.f, 0.f, 0.f};
  gemm_g(w1f, aRow1, lane, acc);
  epilogue1(acc, hA1, n15, quad, b1, ln1w, ln1b);

#pragma unroll
  for (int nt = 0; nt < 8; ++nt) acc[nt] = (floatx4){0.f, 0.f, 0.f, 0.f};
  gemm_g(w2f, aRow0, lane, acc);
  epilogue2(acc, n15, quad, e0, r0, u_lds, ij_lds, b2, ln2w, ln2b, Wo, bo, out);

#pragma unroll
  for (int nt = 0; nt < 8; ++nt) acc[nt] = (floatx4){0.f, 0.f, 0.f, 0.f};
  gemm_g(w2f, aRow1, lane, acc);
  epilogue2(acc, n15, quad, e0 + 16, r0 + 16, u_lds, ij_lds, b2, ln2w, ln2b, Wo, bo, out);
}

extern "C" void kernel_launch(void* const* d_in, const int* in_sizes, int n_in,
                              void* d_out, int out_size, void* d_ws, size_t ws_size,
                              hipStream_t stream) {
  const float* x    = (const float*)d_in[0];
  const float* pos  = (const float*)d_in[1];
  const float* nemb = (const float*)d_in[2];
  const int*   bidx = (const int*)d_in[3];
  const int*   btyp = (const int*)d_in[4];
  const float* bemb = (const float*)d_in[5];
  const float* W0   = (const float*)d_in[6];
  const float* b0   = (const float*)d_in[7];
  const float* W1   = (const float*)d_in[8];
  const float* b1   = (const float*)d_in[9];
  const float* ln1w = (const float*)d_in[10];
  const float* ln1b = (const float*)d_in[11];
  const float* W2   = (const float*)d_in[12];
  const float* b2   = (const float*)d_in[13];
  const float* ln2w = (const float*)d_in[14];
  const float* ln2b = (const float*)d_in[15];
  const float* Wo   = (const float*)d_in[16];
  const float* bo   = (const float*)d_in[17];
  float* out = (float*)d_out;

  // ws: frag weights 128KB + be0 2KB + T 1.31MB + Pa/Pb 51.2MB
  uint16_t* w0ab = (uint16_t*)d_ws;                 // 32768 bf16
  uint16_t* w1f  = w0ab + 32768;                    // 16384
  uint16_t* w2f  = w1f + 16384;                     // 16384
  float*    be0f = (float*)(w2f + 16384);           // 512 f32
  uint16_t* Tt   = (uint16_t*)(be0f + 512);         // 4*TBINS*128 bf16
  uint16_t* Pa   = Tt + (size_t)4 * TBINS * 128;    // N_NODES*128 bf16
  uint16_t* Pb   = Pa + (size_t)N_NODES * 128;      // N_NODES*128 bf16

  const int nblkP = (N_NODES + 64 * PREP_NG - 1) / (64 * PREP_NG);

  prep0_kernel<<<(66048 + out_size + 255) / 256, 256, 0, stream>>>(
      W0, b0, W1, W2, bemb, w0ab, w1f, w2f, be0f, pos, out, out_size);
  prep_tp_kernel<<<TBINS + nblkP, 256, 0, stream>>>(
      W0, be0f, Tt, nemb, w0ab, Pa, Pb);
  bond_mlp_kernel<<<(N_EDGES + 127) / 128, 256, 0, stream>>>(
      x, bidx, btyp, Pa, Pb, Tt, w1f, w2f,
      b1, ln1w, ln1b, b2, ln2w, ln2b, Wo, bo, out);
}

// Round 6
// 354.734 us; speedup vs baseline: 1.3435x; 1.3435x over previous
//
#include <hip/hip_runtime.h>
#include <stdint.h>

#define N_EDGES 500000
#define N_NODES 100000
#define PREP_NG 2     // node-groups per wave in prep_p
#define TBINS 1280    // dist table bins, step 1/32, range [0,40); lerp lookup

typedef __attribute__((ext_vector_type(8))) short short8;
typedef __attribute__((ext_vector_type(4))) float floatx4;
typedef __attribute__((ext_vector_type(2))) float f32x2;

// RNE (one-time prep only)
__device__ __forceinline__ uint16_t f2bf(float f) {
  union { float f; uint32_t u; } cv; cv.f = f;
  uint32_t u = cv.u;
  return (uint16_t)((u + 0x7FFFu + ((u >> 16) & 1u)) >> 16);
}
// truncating pack of two f32 -> bf16x2 (single v_perm_b32)
__device__ __forceinline__ uint32_t pk2bf(float lo, float hi) {
  return __builtin_amdgcn_perm(__float_as_uint(hi), __float_as_uint(lo), 0x07060302u);
}
__device__ __forceinline__ uint16_t bftrunc(float f) {
  return (uint16_t)(__float_as_uint(f) >> 16);
}
__device__ __forceinline__ float lrelu(float v) { return fmaxf(v, 0.001f * v); }

// unpack bf16x2 word -> f32x2 {lo, hi}
__device__ __forceinline__ f32x2 unpk2(uint32_t u) {
  return (f32x2){ __uint_as_float(u << 16), __uint_as_float(u & 0xFFFF0000u) };
}
// h = lrelu(Pa+Pb + lerp(T0,T1,w)) for one bf16x2 word; pk-fp32 math
__device__ __forceinline__ uint32_t comp2(uint32_t a, uint32_t b, uint32_t t0, uint32_t t1,
                                          f32x2 w2) {
  f32x2 p  = unpk2(a) + unpk2(b);
  f32x2 v0 = unpk2(t0), v1 = unpk2(t1);
  f32x2 r  = p + (v0 + w2 * (v1 - v0));
  f32x2 rl = r * 0.001f;
  return pk2bf(fmaxf(r.x, rl.x), fmaxf(r.y, rl.y));
}
__device__ __forceinline__ floatx4 lrelu4(floatx4 v) {
  floatx4 w = v * 0.001f;
  v.x = fmaxf(v.x, w.x); v.y = fmaxf(v.y, w.y);
  v.z = fmaxf(v.z, w.z); v.w = fmaxf(v.w, w.w);
  return v;
}

// ============ prep0: weights -> fragment order; BE0; pos copy; edge records ============
// Edge record (16B): {ux, uy, uz, bits[15:0]=T-row (bt*TBINS+bin), bits[31:16]=w*65536}.
// Precomputing the record removes the bidx->x->dist->T dependent chain from the hot
// kernel: bond phase-1 goes straight record -> gathers (chain depth 3 -> 2).
__global__ void prep0_kernel(const float* __restrict__ W0, const float* __restrict__ b0,
                             const float* __restrict__ W1, const float* __restrict__ W2,
                             const float* __restrict__ bemb,
                             const float* __restrict__ x, const int* __restrict__ bidx,
                             const int* __restrict__ btyp,
                             uint16_t* __restrict__ w0ab, uint16_t* __restrict__ w1f,
                             uint16_t* __restrict__ w2f, float* __restrict__ be0f,
                             float4* __restrict__ erec,
                             const float* __restrict__ pos, float* __restrict__ out, int npos) {
  int id = blockIdx.x * 256 + threadIdx.x;
  if (id < 32768) {                       // w0ab: ks(4) x ntt(16) x lane(64) x j(8)
    int f = id;
    int j = f & 7, lane = (f >> 3) & 63, ntt = (f >> 9) & 15, ks = f >> 13;
    int k = ks * 32 + (lane >> 4) * 8 + j;
    int row = (ntt < 8) ? k : (128 + k);            // ntt<8 -> P_a cols, else P_b cols
    int col = (ntt & 7) * 16 + (lane & 15);
    w0ab[f] = f2bf(W0[row * 128 + col]);
  } else if (id < 49152) {                // w1f
    int f = id - 32768;
    int j = f & 7, lane = (f >> 3) & 63, nt = (f >> 9) & 7, ks = f >> 12;
    int k = ks * 32 + (lane >> 4) * 8 + j;
    w1f[f] = f2bf(W1[k * 128 + nt * 16 + (lane & 15)]);
  } else if (id < 65536) {                // w2f
    int f = id - 49152;
    int j = f & 7, lane = (f >> 3) & 63, nt = (f >> 9) & 7, ks = f >> 12;
    int k = ks * 32 + (lane >> 4) * 8 + j;
    w2f[f] = f2bf(W2[k * 128 + nt * 16 + (lane & 15)]);
  } else if (id < 66048) {                // BE0[t][n] = bond_emb[t]@W0[256:320] + b0 (f32)
    int t = id - 65536; int ty = t >> 7, n = t & 127;
    float s = b0[n];
    for (int kk = 0; kk < 64; ++kk) s += bemb[ty * 64 + kk] * W0[(256 + kk) * 128 + n];
    be0f[t] = s;
  } else if (id - 66048 < npos) {         // pos -> out
    out[id - 66048] = pos[id - 66048];
  } else {                                // edge records
    int e = id - 66048 - npos;
    if (e < N_EDGES) {
      int2 ij = *(const int2*)(bidx + 2 * e);
      int bt = btyp[e];
      float xi0 = x[3 * ij.x], xi1 = x[3 * ij.x + 1], xi2 = x[3 * ij.x + 2];
      float xj0 = x[3 * ij.y], xj1 = x[3 * ij.y + 1], xj2 = x[3 * ij.y + 2];
      float dx = xi0 - xj0, dy = xi1 - xj1, dz = xi2 - xj2;
      float dist = sqrtf(dx * dx + dy * dy + dz * dz);
      float rinv = 1.0f / dist;
      float fb = fminf(dist, 39.5f) * 32.0f;
      int bi = (int)fb;
      uint32_t wq = (uint32_t)((fb - (float)bi) * 65536.0f);
      if (wq > 65535u) wq = 65535u;
      uint32_t pk = (uint32_t)(bt * TBINS + bi) | (wq << 16);
      float4 r;
      r.x = dx * rinv; r.y = dy * rinv; r.z = dz * rinv;
      r.w = __uint_as_float(pk);
      erec[e] = r;
    }
  }
}

// ============ prep_tp: merged T-table + P_a/P_b precompute (independent halves) ============
__global__ __attribute__((amdgpu_flat_work_group_size(256, 256)))
void prep_tp_kernel(const float* __restrict__ W0, const float* __restrict__ be0f,
                    uint16_t* __restrict__ T,
                    const float* __restrict__ nemb, const uint16_t* __restrict__ w0ab,
                    uint16_t* __restrict__ Pa, uint16_t* __restrict__ Pb) {
  __shared__ __align__(16) uint16_t aLds[4 * PREP_NG * 16 * 136];
  __shared__ __align__(16) uint16_t sS[4][16][72];   // per-wave store staging (72 = 64+8 pad)
  __shared__ float rbf[64];
  const int tid = threadIdx.x;

  if (blockIdx.x < TBINS) {
    // ---- T-table half: one block per bin ----
    int b = blockIdx.x;
    float dist = (float)b * (1.0f / 32.0f);
    const float delta = 20.0f / 62.0f;
    const float coeff = -0.5f / (delta * delta);
    if (tid < 64) {
      float v;
      if (tid < 63) { float d = dist - (float)tid * delta; v = __expf(coeff * d * d); }
      else v = (dist >= 20.0f) ? 1.0f : 0.0f;
      rbf[tid] = v;
    }
    __syncthreads();
    float sum = 0.0f;
    for (int k = 0; k < 64; ++k) sum += rbf[k];
    float rs = 1.0f / sum;
    for (int o = tid; o < 512; o += 256) {
      int ty = o >> 7, n = o & 127;
      float s = be0f[ty * 128 + n];
      for (int k = 0; k < 64; ++k) s += rbf[k] * rs * W0[(320 + k) * 128 + n];
      T[((size_t)(ty * TBINS + b)) * 128 + n] = f2bf(s);
    }
    return;
  }

  // ---- P half ----
  const int pblk = blockIdx.x - TBINS;
  const int lane = tid & 63;
  const int wave = tid >> 6;
  const int n15 = lane & 15;
  const int quad = lane >> 4;
  uint16_t* myA = aLds + wave * (PREP_NG * 16 * 136);
  const int base = pblk * (64 * PREP_NG) + wave * (16 * PREP_NG);

  {
    const int le = lane >> 2, sub = lane & 3;
#pragma unroll
    for (int it = 0; it < PREP_NG; ++it) {
      int r = base + it * 16 + le; if (r >= N_NODES) r = N_NODES - 1;
      const float4* src = (const float4*)(nemb + (size_t)r * 128);
#pragma unroll
      for (int g = 0; g < 4; ++g) {
        float4 a = src[sub * 8 + g * 2], b = src[sub * 8 + g * 2 + 1];
        uint4 pk;
        pk.x = pk2bf(a.x, a.y); pk.y = pk2bf(a.z, a.w);
        pk.z = pk2bf(b.x, b.y); pk.w = pk2bf(b.z, b.w);
        *(uint4*)(myA + (it * 16 + le) * 136 + sub * 32 + g * 8) = pk;
      }
    }
  }

  const short8* wfv = (const short8*)w0ab + lane;
  const int srow = lane >> 2, sch = lane & 3;   // store read-back mapping
#pragma unroll
  for (int q = 0; q < 4; ++q) {
    short8 bfr[16];
#pragma unroll
    for (int ks = 0; ks < 4; ++ks)
#pragma unroll
      for (int nq = 0; nq < 4; ++nq)
        bfr[ks * 4 + nq] = wfv[(ks * 16 + q * 4 + nq) * 64];
    uint16_t* dst = (q < 2) ? Pa : Pb;
    const int cbase = (q & 1) * 64;
#pragma unroll
    for (int it = 0; it < PREP_NG; ++it) {
      floatx4 acc[4];
#pragma unroll
      for (int nq = 0; nq < 4; ++nq) acc[nq] = (floatx4){0.f, 0.f, 0.f, 0.f};
#pragma unroll
      for (int ks = 0; ks < 4; ++ks) {
        short8 a = *(const short8*)(myA + (it * 16 + n15) * 136 + ks * 32 + quad * 8);
#pragma unroll
        for (int nq = 0; nq < 4; ++nq)
          acc[nq] = __builtin_amdgcn_mfma_f32_16x16x32_bf16(a, bfr[ks * 4 + nq], acc[nq], 0, 0, 0);
      }
      // stage MFMA-layout acc into LDS, read back row-major, store dwordx4
#pragma unroll
      for (int nq = 0; nq < 4; ++nq)
#pragma unroll
        for (int r = 0; r < 4; ++r)
          sS[wave][quad * 4 + r][nq * 16 + n15] = bftrunc(acc[nq][r]);
      int grow = base + it * 16 + srow;
      if (grow < N_NODES) {
        uint16_t* drow = dst + (size_t)grow * 128 + cbase;
#pragma unroll
        for (int h = 0; h < 2; ++h)
          *(uint4*)(drow + (h * 4 + sch) * 8) =
              *(const uint4*)&sS[wave][srow][(h * 4 + sch) * 8];
      }
    }
  }
}

// GEMM with B-fragments read straight from global (w1f/w2f are 32KB each and
// read by every block -> permanently L1/L2-resident).
__device__ __forceinline__ void gemm_g(const uint16_t* __restrict__ wf, const uint16_t* aRow,
                                       int lane, floatx4* acc) {
  short8 a[4];
#pragma unroll
  for (int ks = 0; ks < 4; ++ks) a[ks] = *(const short8*)(aRow + ks * 32);
  const short8* wv = (const short8*)wf + lane;
#pragma unroll
  for (int ks = 0; ks < 4; ++ks)
#pragma unroll
    for (int nt = 0; nt < 8; ++nt)
      acc[nt] = __builtin_amdgcn_mfma_f32_16x16x32_bf16(a[ks], wv[(ks * 8 + nt) * 64], acc[nt], 0, 0, 0);
}

// ============ main: 64 edges/block, 4 waves, 16 edges/wave (R1 structure) ============
// Phase-1 chain is now: {record, bidx} (both coalesced, L2-hot) -> 16 gathers.
// No x loads, no sqrt, no u_lds/ij_lds (epilogue reads record/bidx coalesced).
__global__ __attribute__((amdgpu_flat_work_group_size(256, 256), amdgpu_waves_per_eu(4)))
void bond_mlp_kernel(const int* __restrict__ bidx,
                     const float4* __restrict__ erec,
                     const uint16_t* __restrict__ Pa, const uint16_t* __restrict__ Pb,
                     const uint16_t* __restrict__ Tt, const uint16_t* __restrict__ w1f,
                     const uint16_t* __restrict__ w2f,
                     const float* __restrict__ b1, const float* __restrict__ ln1w,
                     const float* __restrict__ ln1b,
                     const float* __restrict__ b2, const float* __restrict__ ln2w,
                     const float* __restrict__ ln2b,
                     const float* __restrict__ Wo, const float* __restrict__ bo,
                     float* __restrict__ out) {
  __shared__ __align__(16) uint16_t hA_all[4 * 16 * 136];   // wave-private slices

  const int tid = threadIdx.x;
  const int lane = tid & 63;
  const int wave = tid >> 6;
  const int n15 = lane & 15;
  const int quad = lane >> 4;

  uint16_t* hA = hA_all + wave * (16 * 136);

  // ---- phase 1: h0 = lrelu(Pa[i]+Pb[j]+lerp(T,w)) -> hA (A-layout, bf16) ----
  {
    const int le = lane >> 2, sub = lane & 3;   // 4 lanes per edge
    const int ge = blockIdx.x * 64 + wave * 16 + le;
    const bool valid = ge < N_EDGES;
    int vi = 0, vj = 0;
    uint32_t pk = 0;
    if (valid) {
      int2 ij = *(const int2*)(bidx + 2 * ge);
      vi = ij.x; vj = ij.y;
      pk = __float_as_uint(erec[ge].w);
    }
    int row = pk & 0xFFFFu;
    float w = (float)(pk >> 16) * (1.0f / 65536.0f);
    f32x2 w2 = {w, w};
    const uint4* pa = (const uint4*)(Pa + (size_t)vi * 128 + sub * 32);
    const uint4* pb = (const uint4*)(Pb + (size_t)vj * 128 + sub * 32);
    const uint16_t* trow = Tt + (size_t)row * 128 + sub * 32;
    const uint4* t0p = (const uint4*)trow;
    const uint4* t1p = (const uint4*)(trow + 128);
#pragma unroll
    for (int g = 0; g < 4; ++g) {
      uint4 av = pa[g], bv = pb[g], t0 = t0p[g], t1 = t1p[g];
      uint4 opk;
      opk.x = comp2(av.x, bv.x, t0.x, t1.x, w2);
      opk.y = comp2(av.y, bv.y, t0.y, t1.y, w2);
      opk.z = comp2(av.z, bv.z, t0.z, t1.z, w2);
      opk.w = comp2(av.w, bv.w, t0.w, t1.w, w2);
      *(uint4*)(hA + le * 136 + sub * 32 + g * 8) = opk;
    }
  }
  // no barrier: hA is wave-private; compiler inserts lgkmcnt waits

  const uint16_t* aRow = hA + n15 * 136 + quad * 8;

  floatx4 acc[8];
#pragma unroll
  for (int nt = 0; nt < 8; ++nt) acc[nt] = (floatx4){0.f, 0.f, 0.f, 0.f};
  gemm_g(w1f, aRow, lane, acc);          // L1, B from global (L2-resident)

  // epilogue 1: +b1, LN, lrelu -> hA
  {
    float bv[8], wv[8], bb[8];
#pragma unroll
    for (int nt = 0; nt < 8; ++nt) {
      int col = nt * 16 + n15;
      bv[nt] = b1[col]; wv[nt] = ln1w[col]; bb[nt] = ln1b[col];
    }
    floatx4 s4 = {0.f, 0.f, 0.f, 0.f}, q4 = {0.f, 0.f, 0.f, 0.f};
#pragma unroll
    for (int nt = 0; nt < 8; ++nt) { floatx4 v = acc[nt] + bv[nt]; s4 += v; q4 += v * v; }
#pragma unroll
    for (int m = 1; m <= 8; m <<= 1) {
#pragma unroll
      for (int c = 0; c < 4; ++c) { s4[c] += __shfl_xor(s4[c], m); q4[c] += __shfl_xor(q4[c], m); }
    }
    floatx4 mean = s4 * (1.0f / 128.0f);
    floatx4 var = q4 * (1.0f / 128.0f) - mean * mean;
    floatx4 rstd;
    rstd.x = rsqrtf(var.x + 1e-5f); rstd.y = rsqrtf(var.y + 1e-5f);
    rstd.z = rsqrtf(var.z + 1e-5f); rstd.w = rsqrtf(var.w + 1e-5f);
#pragma unroll
    for (int nt = 0; nt < 8; ++nt) {
      floatx4 v = acc[nt] + bv[nt];
      floatx4 vn = lrelu4((v - mean) * (rstd * wv[nt]) + bb[nt]);
#pragma unroll
      for (int r = 0; r < 4; ++r)
        hA[(quad * 4 + r) * 136 + nt * 16 + n15] = bftrunc(vn[r]);
    }
  }
  // no barrier: hA is wave-private

#pragma unroll
  for (int nt = 0; nt < 8; ++nt) acc[nt] = (floatx4){0.f, 0.f, 0.f, 0.f};
  gemm_g(w2f, aRow, lane, acc);          // L2, B from global (L2-resident)

  // epilogue 2: +b2, LN, lrelu, force = h@Wo + bo, scatter atomics
  {
    float bv[8], wv[8], bb[8], wo0[8], wo1[8];
#pragma unroll
    for (int nt = 0; nt < 8; ++nt) {
      int col = nt * 16 + n15;
      bv[nt] = b2[col]; wv[nt] = ln2w[col]; bb[nt] = ln2b[col];
      wo0[nt] = Wo[2 * col]; wo1[nt] = Wo[2 * col + 1];
    }
    floatx4 s4 = {0.f, 0.f, 0.f, 0.f}, q4 = {0.f, 0.f, 0.f, 0.f};
#pragma unroll
    for (int nt = 0; nt < 8; ++nt) { floatx4 v = acc[nt] + bv[nt]; s4 += v; q4 += v * v; }
#pragma unroll
    for (int m = 1; m <= 8; m <<= 1) {
#pragma unroll
      for (int c = 0; c < 4; ++c) { s4[c] += __shfl_xor(s4[c], m); q4[c] += __shfl_xor(q4[c], m); }
    }
    floatx4 mean = s4 * (1.0f / 128.0f);
    floatx4 var = q4 * (1.0f / 128.0f) - mean * mean;
    floatx4 rstd;
    rstd.x = rsqrtf(var.x + 1e-5f); rstd.y = rsqrtf(var.y + 1e-5f);
    rstd.z = rsqrtf(var.z + 1e-5f); rstd.w = rsqrtf(var.w + 1e-5f);
    floatx4 f0 = {0.f, 0.f, 0.f, 0.f}, f1 = {0.f, 0.f, 0.f, 0.f};
#pragma unroll
    for (int nt = 0; nt < 8; ++nt) {
      floatx4 v = acc[nt] + bv[nt];
      floatx4 vn = lrelu4((v - mean) * (rstd * wv[nt]) + bb[nt]);
      f0 += vn * wo0[nt];
      f1 += vn * wo1[nt];
    }
#pragma unroll
    for (int m = 1; m <= 8; m <<= 1) {
#pragma unroll
      for (int c = 0; c < 4; ++c) { f0[c] += __shfl_xor(f0[c], m); f1[c] += __shfl_xor(f1[c], m); }
    }
    if (n15 < 4) {
      int ge2 = blockIdx.x * 64 + wave * 16 + quad * 4 + n15;
      if (ge2 < N_EDGES) {
        float F0 = (n15 == 0) ? f0.x : (n15 == 1) ? f0.y : (n15 == 2) ? f0.z : f0.w;
        float F1 = (n15 == 0) ? f1.x : (n15 == 1) ? f1.y : (n15 == 2) ? f1.z : f1.w;
        F0 += bo[0]; F1 += bo[1];
        float4 rec = erec[ge2];                       // coalesced: consecutive edges
        int2 ij = *(const int2*)(bidx + 2 * ge2);     // coalesced
        float c0 = 0.5f * F0;          // STEP * force0, along +u
        float c1 = -0.5f * F1;         // STEP * force1, along -u
        atomicAdd(out + 3 * ij.x,     c0 * rec.x);
        atomicAdd(out + 3 * ij.x + 1, c0 * rec.y);
        atomicAdd(out + 3 * ij.x + 2, c0 * rec.z);
        atomicAdd(out + 3 * ij.y,     c1 * rec.x);
        atomicAdd(out + 3 * ij.y + 1, c1 * rec.y);
        atomicAdd(out + 3 * ij.y + 2, c1 * rec.z);
      }
    }
  }
}

extern "C" void kernel_launch(void* const* d_in, const int* in_sizes, int n_in,
                              void* d_out, int out_size, void* d_ws, size_t ws_size,
                              hipStream_t stream) {
  const float* x    = (const float*)d_in[0];
  const float* pos  = (const float*)d_in[1];
  const float* nemb = (const float*)d_in[2];
  const int*   bidx = (const int*)d_in[3];
  const int*   btyp = (const int*)d_in[4];
  const float* bemb = (const float*)d_in[5];
  const float* W0   = (const float*)d_in[6];
  const float* b0   = (const float*)d_in[7];
  const float* W1   = (const float*)d_in[8];
  const float* b1   = (const float*)d_in[9];
  const float* ln1w = (const float*)d_in[10];
  const float* ln1b = (const float*)d_in[11];
  const float* W2   = (const float*)d_in[12];
  const float* b2   = (const float*)d_in[13];
  const float* ln2w = (const float*)d_in[14];
  const float* ln2b = (const float*)d_in[15];
  const float* Wo   = (const float*)d_in[16];
  const float* bo   = (const float*)d_in[17];
  float* out = (float*)d_out;

  // ws: frag weights 128KB + be0 2KB + T 1.31MB + Pa/Pb 51.2MB + erec 8MB
  uint16_t* w0ab = (uint16_t*)d_ws;                 // 32768 bf16
  uint16_t* w1f  = w0ab + 32768;                    // 16384
  uint16_t* w2f  = w1f + 16384;                     // 16384
  float*    be0f = (float*)(w2f + 16384);           // 512 f32
  uint16_t* Tt   = (uint16_t*)(be0f + 512);         // 4*TBINS*128 bf16
  uint16_t* Pa   = Tt + (size_t)4 * TBINS * 128;    // N_NODES*128 bf16
  uint16_t* Pb   = Pa + (size_t)N_NODES * 128;      // N_NODES*128 bf16
  float4*   erec = (float4*)(Pb + (size_t)N_NODES * 128);  // N_EDGES float4

  const int nblkP = (N_NODES + 64 * PREP_NG - 1) / (64 * PREP_NG);
  const int n0 = 66048 + out_size + N_EDGES;        // prep0 threads incl. edge records

  prep0_kernel<<<(n0 + 255) / 256, 256, 0, stream>>>(
      W0, b0, W1, W2, bemb, x, bidx, btyp,
      w0ab, w1f, w2f, be0f, erec, pos, out, out_size);
  prep_tp_kernel<<<TBINS + nblkP, 256, 0, stream>>>(
      W0, be0f, Tt, nemb, w0ab, Pa, Pb);
  bond_mlp_kernel<<<(N_EDGES + 63) / 64, 256, 0, stream>>>(
      bidx, erec, Pa, Pb, Tt, w1f, w2f,
      b1, ln1w, ln1b, b2, ln2w, ln2b, Wo, bo, out);
}

// Round 7
// 352.915 us; speedup vs baseline: 1.3504x; 1.0052x over previous
//
#include <hip/hip_runtime.h>
#include <stdint.h>

#define N_EDGES 500000
#define N_NODES 100000
#define PREP_NG 2     // node-groups per wave in prep_p
#define TBINS 1280    // dist table bins, step 1/32, range [0,40); lerp lookup

typedef __attribute__((ext_vector_type(8))) short short8;
typedef __attribute__((ext_vector_type(4))) float floatx4;
typedef __attribute__((ext_vector_type(2))) float f32x2;

// RNE (one-time prep only)
__device__ __forceinline__ uint16_t f2bf(float f) {
  union { float f; uint32_t u; } cv; cv.f = f;
  uint32_t u = cv.u;
  return (uint16_t)((u + 0x7FFFu + ((u >> 16) & 1u)) >> 16);
}
// truncating pack of two f32 -> bf16x2 (single v_perm_b32)
__device__ __forceinline__ uint32_t pk2bf(float lo, float hi) {
  return __builtin_amdgcn_perm(__float_as_uint(hi), __float_as_uint(lo), 0x07060302u);
}
__device__ __forceinline__ uint16_t bftrunc(float f) {
  return (uint16_t)(__float_as_uint(f) >> 16);
}
__device__ __forceinline__ float lrelu(float v) { return fmaxf(v, 0.001f * v); }

// unpack bf16x2 word -> f32x2 {lo, hi}
__device__ __forceinline__ f32x2 unpk2(uint32_t u) {
  return (f32x2){ __uint_as_float(u << 16), __uint_as_float(u & 0xFFFF0000u) };
}
// h = lrelu(Pa+Pb + lerp(T0,T1,w)) for one bf16x2 word; pk-fp32 math
__device__ __forceinline__ uint32_t comp2(uint32_t a, uint32_t b, uint32_t t0, uint32_t t1,
                                          f32x2 w2) {
  f32x2 p  = unpk2(a) + unpk2(b);
  f32x2 v0 = unpk2(t0), v1 = unpk2(t1);
  f32x2 r  = p + (v0 + w2 * (v1 - v0));
  f32x2 rl = r * 0.001f;
  return pk2bf(fmaxf(r.x, rl.x), fmaxf(r.y, rl.y));
}
__device__ __forceinline__ floatx4 lrelu4(floatx4 v) {
  floatx4 w = v * 0.001f;
  v.x = fmaxf(v.x, w.x); v.y = fmaxf(v.y, w.y);
  v.z = fmaxf(v.z, w.z); v.w = fmaxf(v.w, w.w);
  return v;
}

// ============ prep0: weights -> fragment order; BE0; pos copy; edge records ============
// Edge record (16B): {ux, uy, uz, bits[15:0]=T-row (bt*TBINS+bin), bits[31:16]=w*65536}.
__global__ void prep0_kernel(const float* __restrict__ W0, const float* __restrict__ b0,
                             const float* __restrict__ W1, const float* __restrict__ W2,
                             const float* __restrict__ bemb,
                             const float* __restrict__ x, const int* __restrict__ bidx,
                             const int* __restrict__ btyp,
                             uint16_t* __restrict__ w0ab, uint16_t* __restrict__ w1f,
                             uint16_t* __restrict__ w2f, float* __restrict__ be0f,
                             float4* __restrict__ erec,
                             const float* __restrict__ pos, float* __restrict__ out, int npos) {
  int id = blockIdx.x * 256 + threadIdx.x;
  if (id < 32768) {                       // w0ab: ks(4) x ntt(16) x lane(64) x j(8)
    int f = id;
    int j = f & 7, lane = (f >> 3) & 63, ntt = (f >> 9) & 15, ks = f >> 13;
    int k = ks * 32 + (lane >> 4) * 8 + j;
    int row = (ntt < 8) ? k : (128 + k);            // ntt<8 -> P_a cols, else P_b cols
    int col = (ntt & 7) * 16 + (lane & 15);
    w0ab[f] = f2bf(W0[row * 128 + col]);
  } else if (id < 49152) {                // w1f
    int f = id - 32768;
    int j = f & 7, lane = (f >> 3) & 63, nt = (f >> 9) & 7, ks = f >> 12;
    int k = ks * 32 + (lane >> 4) * 8 + j;
    w1f[f] = f2bf(W1[k * 128 + nt * 16 + (lane & 15)]);
  } else if (id < 65536) {                // w2f
    int f = id - 49152;
    int j = f & 7, lane = (f >> 3) & 63, nt = (f >> 9) & 7, ks = f >> 12;
    int k = ks * 32 + (lane >> 4) * 8 + j;
    w2f[f] = f2bf(W2[k * 128 + nt * 16 + (lane & 15)]);
  } else if (id < 66048) {                // BE0[t][n] = bond_emb[t]@W0[256:320] + b0 (f32)
    int t = id - 65536; int ty = t >> 7, n = t & 127;
    float s = b0[n];
    for (int kk = 0; kk < 64; ++kk) s += bemb[ty * 64 + kk] * W0[(256 + kk) * 128 + n];
    be0f[t] = s;
  } else if (id - 66048 < npos) {         // pos -> out
    out[id - 66048] = pos[id - 66048];
  } else {                                // edge records
    int e = id - 66048 - npos;
    if (e < N_EDGES) {
      int2 ij = *(const int2*)(bidx + 2 * e);
      int bt = btyp[e];
      float xi0 = x[3 * ij.x], xi1 = x[3 * ij.x + 1], xi2 = x[3 * ij.x + 2];
      float xj0 = x[3 * ij.y], xj1 = x[3 * ij.y + 1], xj2 = x[3 * ij.y + 2];
      float dx = xi0 - xj0, dy = xi1 - xj1, dz = xi2 - xj2;
      float dist = sqrtf(dx * dx + dy * dy + dz * dz);
      float rinv = 1.0f / dist;
      float fb = fminf(dist, 39.5f) * 32.0f;
      int bi = (int)fb;
      uint32_t wq = (uint32_t)((fb - (float)bi) * 65536.0f);
      if (wq > 65535u) wq = 65535u;
      uint32_t pk = (uint32_t)(bt * TBINS + bi) | (wq << 16);
      float4 r;
      r.x = dx * rinv; r.y = dy * rinv; r.z = dz * rinv;
      r.w = __uint_as_float(pk);
      erec[e] = r;
    }
  }
}

// ============ prep_tp: merged T-table + P_a/P_b precompute (independent halves) ============
__global__ __attribute__((amdgpu_flat_work_group_size(256, 256)))
void prep_tp_kernel(const float* __restrict__ W0, const float* __restrict__ be0f,
                    uint16_t* __restrict__ T,
                    const float* __restrict__ nemb, const uint16_t* __restrict__ w0ab,
                    uint16_t* __restrict__ Pa, uint16_t* __restrict__ Pb) {
  __shared__ __align__(16) uint16_t aLds[4 * PREP_NG * 16 * 136];
  __shared__ __align__(16) uint16_t sS[4][16][72];   // per-wave store staging (72 = 64+8 pad)
  __shared__ float rbf[64];
  const int tid = threadIdx.x;

  if (blockIdx.x < TBINS) {
    // ---- T-table half: one block per bin ----
    int b = blockIdx.x;
    float dist = (float)b * (1.0f / 32.0f);
    const float delta = 20.0f / 62.0f;
    const float coeff = -0.5f / (delta * delta);
    if (tid < 64) {
      float v;
      if (tid < 63) { float d = dist - (float)tid * delta; v = __expf(coeff * d * d); }
      else v = (dist >= 20.0f) ? 1.0f : 0.0f;
      rbf[tid] = v;
    }
    __syncthreads();
    float sum = 0.0f;
    for (int k = 0; k < 64; ++k) sum += rbf[k];
    float rs = 1.0f / sum;
    for (int o = tid; o < 512; o += 256) {
      int ty = o >> 7, n = o & 127;
      float s = be0f[ty * 128 + n];
      for (int k = 0; k < 64; ++k) s += rbf[k] * rs * W0[(320 + k) * 128 + n];
      T[((size_t)(ty * TBINS + b)) * 128 + n] = f2bf(s);
    }
    return;
  }

  // ---- P half ----
  const int pblk = blockIdx.x - TBINS;
  const int lane = tid & 63;
  const int wave = tid >> 6;
  const int n15 = lane & 15;
  const int quad = lane >> 4;
  uint16_t* myA = aLds + wave * (PREP_NG * 16 * 136);
  const int base = pblk * (64 * PREP_NG) + wave * (16 * PREP_NG);

  {
    const int le = lane >> 2, sub = lane & 3;
#pragma unroll
    for (int it = 0; it < PREP_NG; ++it) {
      int r = base + it * 16 + le; if (r >= N_NODES) r = N_NODES - 1;
      const float4* src = (const float4*)(nemb + (size_t)r * 128);
#pragma unroll
      for (int g = 0; g < 4; ++g) {
        float4 a = src[sub * 8 + g * 2], b = src[sub * 8 + g * 2 + 1];
        uint4 pk;
        pk.x = pk2bf(a.x, a.y); pk.y = pk2bf(a.z, a.w);
        pk.z = pk2bf(b.x, b.y); pk.w = pk2bf(b.z, b.w);
        *(uint4*)(myA + (it * 16 + le) * 136 + sub * 32 + g * 8) = pk;
      }
    }
  }

  const short8* wfv = (const short8*)w0ab + lane;
  const int srow = lane >> 2, sch = lane & 3;   // store read-back mapping
#pragma unroll
  for (int q = 0; q < 4; ++q) {
    short8 bfr[16];
#pragma unroll
    for (int ks = 0; ks < 4; ++ks)
#pragma unroll
      for (int nq = 0; nq < 4; ++nq)
        bfr[ks * 4 + nq] = wfv[(ks * 16 + q * 4 + nq) * 64];
    uint16_t* dst = (q < 2) ? Pa : Pb;
    const int cbase = (q & 1) * 64;
#pragma unroll
    for (int it = 0; it < PREP_NG; ++it) {
      floatx4 acc[4];
#pragma unroll
      for (int nq = 0; nq < 4; ++nq) acc[nq] = (floatx4){0.f, 0.f, 0.f, 0.f};
#pragma unroll
      for (int ks = 0; ks < 4; ++ks) {
        short8 a = *(const short8*)(myA + (it * 16 + n15) * 136 + ks * 32 + quad * 8);
#pragma unroll
        for (int nq = 0; nq < 4; ++nq)
          acc[nq] = __builtin_amdgcn_mfma_f32_16x16x32_bf16(a, bfr[ks * 4 + nq], acc[nq], 0, 0, 0);
      }
      // stage MFMA-layout acc into LDS, read back row-major, store dwordx4
#pragma unroll
      for (int nq = 0; nq < 4; ++nq)
#pragma unroll
        for (int r = 0; r < 4; ++r)
          sS[wave][quad * 4 + r][nq * 16 + n15] = bftrunc(acc[nq][r]);
      int grow = base + it * 16 + srow;
      if (grow < N_NODES) {
        uint16_t* drow = dst + (size_t)grow * 128 + cbase;
#pragma unroll
        for (int h = 0; h < 2; ++h)
          *(uint4*)(drow + (h * 4 + sch) * 8) =
              *(const uint4*)&sS[wave][srow][(h * 4 + sch) * 8];
      }
    }
  }
}

// GEMM with B-fragments read straight from global (w1f/w2f are 32KB each and
// read by every block -> permanently L1/L2-resident).
__device__ __forceinline__ void gemm_g(const uint16_t* __restrict__ wf, const uint16_t* aRow,
                                       int lane, floatx4* acc) {
  short8 a[4];
#pragma unroll
  for (int ks = 0; ks < 4; ++ks) a[ks] = *(const short8*)(aRow + ks * 32);
  const short8* wv = (const short8*)wf + lane;
#pragma unroll
  for (int ks = 0; ks < 4; ++ks)
#pragma unroll
    for (int nt = 0; nt < 8; ++nt)
      acc[nt] = __builtin_amdgcn_mfma_f32_16x16x32_bf16(a[ks], wv[(ks * 8 + nt) * 64], acc[nt], 0, 0, 0);
}

// ============ main: 64 edges/block, 4 waves, 16 edges/wave ============
// COALESCED GATHERS: within each gather instruction the 4 lanes of an edge now
// read CONSECUTIVE 16B of the SAME 64B line (lane reads byte g*64 + sub*16 of the
// row) instead of the first 16B of 4 different lines (was sub*64 + g*16). One
// instruction touches 16 lines, not 64 -> 4x fewer TA line-cycles on all four
// gather streams. Bit-identical math; only the address<->register permutation
// and the matching LDS store offsets change.
__global__ __attribute__((amdgpu_flat_work_group_size(256, 256), amdgpu_waves_per_eu(4)))
void bond_mlp_kernel(const int* __restrict__ bidx,
                     const float4* __restrict__ erec,
                     const uint16_t* __restrict__ Pa, const uint16_t* __restrict__ Pb,
                     const uint16_t* __restrict__ Tt, const uint16_t* __restrict__ w1f,
                     const uint16_t* __restrict__ w2f,
                     const float* __restrict__ b1, const float* __restrict__ ln1w,
                     const float* __restrict__ ln1b,
                     const float* __restrict__ b2, const float* __restrict__ ln2w,
                     const float* __restrict__ ln2b,
                     const float* __restrict__ Wo, const float* __restrict__ bo,
                     float* __restrict__ out) {
  __shared__ __align__(16) uint16_t hA_all[4 * 16 * 136];   // wave-private slices

  const int tid = threadIdx.x;
  const int lane = tid & 63;
  const int wave = tid >> 6;
  const int n15 = lane & 15;
  const int quad = lane >> 4;

  uint16_t* hA = hA_all + wave * (16 * 136);

  // ---- phase 1: h0 = lrelu(Pa[i]+Pb[j]+lerp(T,w)) -> hA (A-layout, bf16) ----
  {
    const int le = lane >> 2, sub = lane & 3;   // 4 lanes per edge
    const int ge = blockIdx.x * 64 + wave * 16 + le;
    const bool valid = ge < N_EDGES;
    int vi = 0, vj = 0;
    uint32_t pk = 0;
    if (valid) {
      int2 ij = *(const int2*)(bidx + 2 * ge);
      vi = ij.x; vj = ij.y;
      pk = __float_as_uint(erec[ge].w);
    }
    int row = pk & 0xFFFFu;
    float w = (float)(pk >> 16) * (1.0f / 65536.0f);
    f32x2 w2 = {w, w};
    // lane (le,sub) reads bytes [g*64 + sub*16, +16) of each 256B row:
    // instruction g's 4 edge-lanes hit consecutive 16B of ONE 64B line.
    const uint4* pa = (const uint4*)(Pa + (size_t)vi * 128 + sub * 8);
    const uint4* pb = (const uint4*)(Pb + (size_t)vj * 128 + sub * 8);
    const uint16_t* trow = Tt + (size_t)row * 128 + sub * 8;
    const uint4* t0p = (const uint4*)trow;
    const uint4* t1p = (const uint4*)(trow + 128);
#pragma unroll
    for (int g = 0; g < 4; ++g) {
      uint4 av = pa[g * 4], bv = pb[g * 4], t0 = t0p[g * 4], t1 = t1p[g * 4];
      uint4 opk;
      opk.x = comp2(av.x, bv.x, t0.x, t1.x, w2);
      opk.y = comp2(av.y, bv.y, t0.y, t1.y, w2);
      opk.z = comp2(av.z, bv.z, t0.z, t1.z, w2);
      opk.w = comp2(av.w, bv.w, t0.w, t1.w, w2);
      *(uint4*)(hA + le * 136 + g * 32 + sub * 8) = opk;   // matching permuted store
    }
  }
  // no barrier: hA is wave-private; compiler inserts lgkmcnt waits

  const uint16_t* aRow = hA + n15 * 136 + quad * 8;

  floatx4 acc[8];
#pragma unroll
  for (int nt = 0; nt < 8; ++nt) acc[nt] = (floatx4){0.f, 0.f, 0.f, 0.f};
  gemm_g(w1f, aRow, lane, acc);          // L1, B from global (L2-resident)

  // epilogue 1: +b1, LN, lrelu -> hA
  {
    float bv[8], wv[8], bb[8];
#pragma unroll
    for (int nt = 0; nt < 8; ++nt) {
      int col = nt * 16 + n15;
      bv[nt] = b1[col]; wv[nt] = ln1w[col]; bb[nt] = ln1b[col];
    }
    floatx4 s4 = {0.f, 0.f, 0.f, 0.f}, q4 = {0.f, 0.f, 0.f, 0.f};
#pragma unroll
    for (int nt = 0; nt < 8; ++nt) { floatx4 v = acc[nt] + bv[nt]; s4 += v; q4 += v * v; }
#pragma unroll
    for (int m = 1; m <= 8; m <<= 1) {
#pragma unroll
      for (int c = 0; c < 4; ++c) { s4[c] += __shfl_xor(s4[c], m); q4[c] += __shfl_xor(q4[c], m); }
    }
    floatx4 mean = s4 * (1.0f / 128.0f);
    floatx4 var = q4 * (1.0f / 128.0f) - mean * mean;
    floatx4 rstd;
    rstd.x = rsqrtf(var.x + 1e-5f); rstd.y = rsqrtf(var.y + 1e-5f);
    rstd.z = rsqrtf(var.z + 1e-5f); rstd.w = rsqrtf(var.w + 1e-5f);
#pragma unroll
    for (int nt = 0; nt < 8; ++nt) {
      floatx4 v = acc[nt] + bv[nt];
      floatx4 vn = lrelu4((v - mean) * (rstd * wv[nt]) + bb[nt]);
#pragma unroll
      for (int r = 0; r < 4; ++r)
        hA[(quad * 4 + r) * 136 + nt * 16 + n15] = bftrunc(vn[r]);
    }
  }
  // no barrier: hA is wave-private

#pragma unroll
  for (int nt = 0; nt < 8; ++nt) acc[nt] = (floatx4){0.f, 0.f, 0.f, 0.f};
  gemm_g(w2f, aRow, lane, acc);          // L2, B from global (L2-resident)

  // epilogue 2: +b2, LN, lrelu, force = h@Wo + bo, scatter atomics
  {
    float bv[8], wv[8], bb[8], wo0[8], wo1[8];
#pragma unroll
    for (int nt = 0; nt < 8; ++nt) {
      int col = nt * 16 + n15;
      bv[nt] = b2[col]; wv[nt] = ln2w[col]; bb[nt] = ln2b[col];
      wo0[nt] = Wo[2 * col]; wo1[nt] = Wo[2 * col + 1];
    }
    floatx4 s4 = {0.f, 0.f, 0.f, 0.f}, q4 = {0.f, 0.f, 0.f, 0.f};
#pragma unroll
    for (int nt = 0; nt < 8; ++nt) { floatx4 v = acc[nt] + bv[nt]; s4 += v; q4 += v * v; }
#pragma unroll
    for (int m = 1; m <= 8; m <<= 1) {
#pragma unroll
      for (int c = 0; c < 4; ++c) { s4[c] += __shfl_xor(s4[c], m); q4[c] += __shfl_xor(q4[c], m); }
    }
    floatx4 mean = s4 * (1.0f / 128.0f);
    floatx4 var = q4 * (1.0f / 128.0f) - mean * mean;
    floatx4 rstd;
    rstd.x = rsqrtf(var.x + 1e-5f); rstd.y = rsqrtf(var.y + 1e-5f);
    rstd.z = rsqrtf(var.z + 1e-5f); rstd.w = rsqrtf(var.w + 1e-5f);
    floatx4 f0 = {0.f, 0.f, 0.f, 0.f}, f1 = {0.f, 0.f, 0.f, 0.f};
#pragma unroll
    for (int nt = 0; nt < 8; ++nt) {
      floatx4 v = acc[nt] + bv[nt];
      floatx4 vn = lrelu4((v - mean) * (rstd * wv[nt]) + bb[nt]);
      f0 += vn * wo0[nt];
      f1 += vn * wo1[nt];
    }
#pragma unroll
    for (int m = 1; m <= 8; m <<= 1) {
#pragma unroll
      for (int c = 0; c < 4; ++c) { f0[c] += __shfl_xor(f0[c], m); f1[c] += __shfl_xor(f1[c], m); }
    }
    if (n15 < 4) {
      int ge2 = blockIdx.x * 64 + wave * 16 + quad * 4 + n15;
      if (ge2 < N_EDGES) {
        float F0 = (n15 == 0) ? f0.x : (n15 == 1) ? f0.y : (n15 == 2) ? f0.z : f0.w;
        float F1 = (n15 == 0) ? f1.x : (n15 == 1) ? f1.y : (n15 == 2) ? f1.z : f1.w;
        F0 += bo[0]; F1 += bo[1];
        float4 rec = erec[ge2];                       // coalesced: consecutive edges
        int2 ij = *(const int2*)(bidx + 2 * ge2);     // coalesced
        float c0 = 0.5f * F0;          // STEP * force0, along +u
        float c1 = -0.5f * F1;         // STEP * force1, along -u
        atomicAdd(out + 3 * ij.x,     c0 * rec.x);
        atomicAdd(out + 3 * ij.x + 1, c0 * rec.y);
        atomicAdd(out + 3 * ij.x + 2, c0 * rec.z);
        atomicAdd(out + 3 * ij.y,     c1 * rec.x);
        atomicAdd(out + 3 * ij.y + 1, c1 * rec.y);
        atomicAdd(out + 3 * ij.y + 2, c1 * rec.z);
      }
    }
  }
}

extern "C" void kernel_launch(void* const* d_in, const int* in_sizes, int n_in,
                              void* d_out, int out_size, void* d_ws, size_t ws_size,
                              hipStream_t stream) {
  const float* x    = (const float*)d_in[0];
  const float* pos  = (const float*)d_in[1];
  const float* nemb = (const float*)d_in[2];
  const int*   bidx = (const int*)d_in[3];
  const int*   btyp = (const int*)d_in[4];
  const float* bemb = (const float*)d_in[5];
  const float* W0   = (const float*)d_in[6];
  const float* b0   = (const float*)d_in[7];
  const float* W1   = (const float*)d_in[8];
  const float* b1   = (const float*)d_in[9];
  const float* ln1w = (const float*)d_in[10];
  const float* ln1b = (const float*)d_in[11];
  const float* W2   = (const float*)d_in[12];
  const float* b2   = (const float*)d_in[13];
  const float* ln2w = (const float*)d_in[14];
  const float* ln2b = (const float*)d_in[15];
  const float* Wo   = (const float*)d_in[16];
  const float* bo   = (const float*)d_in[17];
  float* out = (float*)d_out;

  // ws: frag weights 128KB + be0 2KB + T 1.31MB + Pa/Pb 51.2MB + erec 8MB
  uint16_t* w0ab = (uint16_t*)d_ws;                 // 32768 bf16
  uint16_t* w1f  = w0ab + 32768;                    // 16384
  uint16_t* w2f  = w1f + 16384;                     // 16384
  float*    be0f = (float*)(w2f + 16384);           // 512 f32
  uint16_t* Tt   = (uint16_t*)(be0f + 512);         // 4*TBINS*128 bf16
  uint16_t* Pa   = Tt + (size_t)4 * TBINS * 128;    // N_NODES*128 bf16
  uint16_t* Pb   = Pa + (size_t)N_NODES * 128;      // N_NODES*128 bf16
  float4*   erec = (float4*)(Pb + (size_t)N_NODES * 128);  // N_EDGES float4

  const int nblkP = (N_NODES + 64 * PREP_NG - 1) / (64 * PREP_NG);
  const int n0 = 66048 + out_size + N_EDGES;        // prep0 threads incl. edge records

  prep0_kernel<<<(n0 + 255) / 256, 256, 0, stream>>>(
      W0, b0, W1, W2, bemb, x, bidx, btyp,
      w0ab, w1f, w2f, be0f, erec, pos, out, out_size);
  prep_tp_kernel<<<TBINS + nblkP, 256, 0, stream>>>(
      W0, be0f, Tt, nemb, w0ab, Pa, Pb);
  bond_mlp_kernel<<<(N_EDGES + 63) / 64, 256, 0, stream>>>(
      bidx, erec, Pa, Pb, Tt, w1f, w2f,
      b1, ln1w, ln1b, b2, ln2w, ln2b, Wo, bo, out);
}

// Round 8
// 348.121 us; speedup vs baseline: 1.3690x; 1.0138x over previous
//
#include <hip/hip_runtime.h>
#include <stdint.h>

#define N_EDGES 500000
#define N_NODES 100000
#define PREP_NG 2     // node-groups per wave in prep_p
#define TBINS 1280    // dist table bins, step 1/32, range [0,40); lerp lookup

typedef __attribute__((ext_vector_type(8))) short short8;
typedef __attribute__((ext_vector_type(4))) float floatx4;
typedef __attribute__((ext_vector_type(2))) float f32x2;

// RNE (one-time prep only)
__device__ __forceinline__ uint16_t f2bf(float f) {
  union { float f; uint32_t u; } cv; cv.f = f;
  uint32_t u = cv.u;
  return (uint16_t)((u + 0x7FFFu + ((u >> 16) & 1u)) >> 16);
}
// truncating pack of two f32 -> bf16x2 (single v_perm_b32)
__device__ __forceinline__ uint32_t pk2bf(float lo, float hi) {
  return __builtin_amdgcn_perm(__float_as_uint(hi), __float_as_uint(lo), 0x07060302u);
}
__device__ __forceinline__ uint16_t bftrunc(float f) {
  return (uint16_t)(__float_as_uint(f) >> 16);
}
__device__ __forceinline__ float lrelu(float v) { return fmaxf(v, 0.001f * v); }

// unpack bf16x2 word -> f32x2 {lo, hi}
__device__ __forceinline__ f32x2 unpk2(uint32_t u) {
  return (f32x2){ __uint_as_float(u << 16), __uint_as_float(u & 0xFFFF0000u) };
}
// h = lrelu(Pa+Pb + lerp(T0,T1,w)) for one bf16x2 word; pk-fp32 math
__device__ __forceinline__ uint32_t comp2(uint32_t a, uint32_t b, uint32_t t0, uint32_t t1,
                                          f32x2 w2) {
  f32x2 p  = unpk2(a) + unpk2(b);
  f32x2 v0 = unpk2(t0), v1 = unpk2(t1);
  f32x2 r  = p + (v0 + w2 * (v1 - v0));
  f32x2 rl = r * 0.001f;
  return pk2bf(fmaxf(r.x, rl.x), fmaxf(r.y, rl.y));
}
__device__ __forceinline__ floatx4 lrelu4(floatx4 v) {
  floatx4 w = v * 0.001f;
  v.x = fmaxf(v.x, w.x); v.y = fmaxf(v.y, w.y);
  v.z = fmaxf(v.z, w.z); v.w = fmaxf(v.w, w.w);
  return v;
}

// ============ prep0: weights -> fragment order; BE0; pos copy; edge records ============
// Edge record (16B): {ux, uy, uz, bits[15:0]=T-row (bt*TBINS+bin), bits[31:16]=w*65536}.
__global__ void prep0_kernel(const float* __restrict__ W0, const float* __restrict__ b0,
                             const float* __restrict__ W1, const float* __restrict__ W2,
                             const float* __restrict__ bemb,
                             const float* __restrict__ x, const int* __restrict__ bidx,
                             const int* __restrict__ btyp,
                             uint16_t* __restrict__ w0ab, uint16_t* __restrict__ w1f,
                             uint16_t* __restrict__ w2f, float* __restrict__ be0f,
                             float4* __restrict__ erec,
                             const float* __restrict__ pos, float* __restrict__ out, int npos) {
  int id = blockIdx.x * 256 + threadIdx.x;
  if (id < 32768) {                       // w0ab: ks(4) x ntt(16) x lane(64) x j(8)
    int f = id;
    int j = f & 7, lane = (f >> 3) & 63, ntt = (f >> 9) & 15, ks = f >> 13;
    int k = ks * 32 + (lane >> 4) * 8 + j;
    int row = (ntt < 8) ? k : (128 + k);            // ntt<8 -> P_a cols, else P_b cols
    int col = (ntt & 7) * 16 + (lane & 15);
    w0ab[f] = f2bf(W0[row * 128 + col]);
  } else if (id < 49152) {                // w1f
    int f = id - 32768;
    int j = f & 7, lane = (f >> 3) & 63, nt = (f >> 9) & 7, ks = f >> 12;
    int k = ks * 32 + (lane >> 4) * 8 + j;
    w1f[f] = f2bf(W1[k * 128 + nt * 16 + (lane & 15)]);
  } else if (id < 65536) {                // w2f
    int f = id - 49152;
    int j = f & 7, lane = (f >> 3) & 63, nt = (f >> 9) & 7, ks = f >> 12;
    int k = ks * 32 + (lane >> 4) * 8 + j;
    w2f[f] = f2bf(W2[k * 128 + nt * 16 + (lane & 15)]);
  } else if (id < 66048) {                // BE0[t][n] = bond_emb[t]@W0[256:320] + b0 (f32)
    int t = id - 65536; int ty = t >> 7, n = t & 127;
    float s = b0[n];
    for (int kk = 0; kk < 64; ++kk) s += bemb[ty * 64 + kk] * W0[(256 + kk) * 128 + n];
    be0f[t] = s;
  } else if (id - 66048 < npos) {         // pos -> out
    out[id - 66048] = pos[id - 66048];
  } else {                                // edge records
    int e = id - 66048 - npos;
    if (e < N_EDGES) {
      int2 ij = *(const int2*)(bidx + 2 * e);
      int bt = btyp[e];
      float xi0 = x[3 * ij.x], xi1 = x[3 * ij.x + 1], xi2 = x[3 * ij.x + 2];
      float xj0 = x[3 * ij.y], xj1 = x[3 * ij.y + 1], xj2 = x[3 * ij.y + 2];
      float dx = xi0 - xj0, dy = xi1 - xj1, dz = xi2 - xj2;
      float dist = sqrtf(dx * dx + dy * dy + dz * dz);
      float rinv = 1.0f / dist;
      float fb = fminf(dist, 39.5f) * 32.0f;
      int bi = (int)fb;
      uint32_t wq = (uint32_t)((fb - (float)bi) * 65536.0f);
      if (wq > 65535u) wq = 65535u;
      uint32_t pk = (uint32_t)(bt * TBINS + bi) | (wq << 16);
      float4 r;
      r.x = dx * rinv; r.y = dy * rinv; r.z = dz * rinv;
      r.w = __uint_as_float(pk);
      erec[e] = r;
    }
  }
}

// ============ prep_tp: merged T-table + P_a/P_b precompute (independent halves) ============
__global__ __attribute__((amdgpu_flat_work_group_size(256, 256)))
void prep_tp_kernel(const float* __restrict__ W0, const float* __restrict__ be0f,
                    uint16_t* __restrict__ T,
                    const float* __restrict__ nemb, const uint16_t* __restrict__ w0ab,
                    uint16_t* __restrict__ Pa, uint16_t* __restrict__ Pb) {
  __shared__ __align__(16) uint16_t aLds[4 * PREP_NG * 16 * 136];
  __shared__ __align__(16) uint16_t sS[4][16][72];   // per-wave store staging (72 = 64+8 pad)
  __shared__ float rbf[64];
  const int tid = threadIdx.x;

  if (blockIdx.x < TBINS) {
    // ---- T-table half: one block per bin ----
    int b = blockIdx.x;
    float dist = (float)b * (1.0f / 32.0f);
    const float delta = 20.0f / 62.0f;
    const float coeff = -0.5f / (delta * delta);
    if (tid < 64) {
      float v;
      if (tid < 63) { float d = dist - (float)tid * delta; v = __expf(coeff * d * d); }
      else v = (dist >= 20.0f) ? 1.0f : 0.0f;
      rbf[tid] = v;
    }
    __syncthreads();
    float sum = 0.0f;
    for (int k = 0; k < 64; ++k) sum += rbf[k];
    float rs = 1.0f / sum;
    for (int o = tid; o < 512; o += 256) {
      int ty = o >> 7, n = o & 127;
      float s = be0f[ty * 128 + n];
      for (int k = 0; k < 64; ++k) s += rbf[k] * rs * W0[(320 + k) * 128 + n];
      T[((size_t)(ty * TBINS + b)) * 128 + n] = f2bf(s);
    }
    return;
  }

  // ---- P half ----
  const int pblk = blockIdx.x - TBINS;
  const int lane = tid & 63;
  const int wave = tid >> 6;
  const int n15 = lane & 15;
  const int quad = lane >> 4;
  uint16_t* myA = aLds + wave * (PREP_NG * 16 * 136);
  const int base = pblk * (64 * PREP_NG) + wave * (16 * PREP_NG);

  {
    const int le = lane >> 2, sub = lane & 3;
#pragma unroll
    for (int it = 0; it < PREP_NG; ++it) {
      int r = base + it * 16 + le; if (r >= N_NODES) r = N_NODES - 1;
      const float4* src = (const float4*)(nemb + (size_t)r * 128);
#pragma unroll
      for (int g = 0; g < 4; ++g) {
        float4 a = src[sub * 8 + g * 2], b = src[sub * 8 + g * 2 + 1];
        uint4 pk;
        pk.x = pk2bf(a.x, a.y); pk.y = pk2bf(a.z, a.w);
        pk.z = pk2bf(b.x, b.y); pk.w = pk2bf(b.z, b.w);
        *(uint4*)(myA + (it * 16 + le) * 136 + sub * 32 + g * 8) = pk;
      }
    }
  }

  const short8* wfv = (const short8*)w0ab + lane;
  const int srow = lane >> 2, sch = lane & 3;   // store read-back mapping
#pragma unroll
  for (int q = 0; q < 4; ++q) {
    short8 bfr[16];
#pragma unroll
    for (int ks = 0; ks < 4; ++ks)
#pragma unroll
      for (int nq = 0; nq < 4; ++nq)
        bfr[ks * 4 + nq] = wfv[(ks * 16 + q * 4 + nq) * 64];
    uint16_t* dst = (q < 2) ? Pa : Pb;
    const int cbase = (q & 1) * 64;
#pragma unroll
    for (int it = 0; it < PREP_NG; ++it) {
      floatx4 acc[4];
#pragma unroll
      for (int nq = 0; nq < 4; ++nq) acc[nq] = (floatx4){0.f, 0.f, 0.f, 0.f};
#pragma unroll
      for (int ks = 0; ks < 4; ++ks) {
        short8 a = *(const short8*)(myA + (it * 16 + n15) * 136 + ks * 32 + quad * 8);
#pragma unroll
        for (int nq = 0; nq < 4; ++nq)
          acc[nq] = __builtin_amdgcn_mfma_f32_16x16x32_bf16(a, bfr[ks * 4 + nq], acc[nq], 0, 0, 0);
      }
      // stage MFMA-layout acc into LDS, read back row-major, store dwordx4
#pragma unroll
      for (int nq = 0; nq < 4; ++nq)
#pragma unroll
        for (int r = 0; r < 4; ++r)
          sS[wave][quad * 4 + r][nq * 16 + n15] = bftrunc(acc[nq][r]);
      int grow = base + it * 16 + srow;
      if (grow < N_NODES) {
        uint16_t* drow = dst + (size_t)grow * 128 + cbase;
#pragma unroll
        for (int h = 0; h < 2; ++h)
          *(uint4*)(drow + (h * 4 + sch) * 8) =
              *(const uint4*)&sS[wave][srow][(h * 4 + sch) * 8];
      }
    }
  }
}

// GEMM with B-fragments from global, SOFTWARE-PIPELINED: 8 loads are batched into
// a named register buffer while the previous batch feeds MFMAs (double-buffered,
// ks fully unrolled so all indices are compile-time -> registers, no scratch).
// This is the fix for the VGPR=56 compile that serialized load->wait->MFMA 64x
// at ~200cy L2-hit each (the dominant stall, ~26k cy/pass).
__device__ __forceinline__ void gemm_g(const uint16_t* __restrict__ wf, const uint16_t* aRow,
                                       int lane, floatx4* acc) {
  short8 a[4];
#pragma unroll
  for (int ks = 0; ks < 4; ++ks) a[ks] = *(const short8*)(aRow + ks * 32);
  const short8* wv = (const short8*)wf + lane;
  short8 bA[8], bB[8];
#pragma unroll
  for (int nt = 0; nt < 8; ++nt) bA[nt] = wv[nt * 64];        // prefetch ks=0 batch
#pragma unroll
  for (int ks = 0; ks < 4; ++ks) {
    short8* cur = (ks & 1) ? bB : bA;   // static per unrolled iteration
    short8* nxt = (ks & 1) ? bA : bB;
    if (ks < 3) {
#pragma unroll
      for (int nt = 0; nt < 8; ++nt) nxt[nt] = wv[((ks + 1) * 8 + nt) * 64];
    }
#pragma unroll
    for (int nt = 0; nt < 8; ++nt)
      acc[nt] = __builtin_amdgcn_mfma_f32_16x16x32_bf16(a[ks], cur[nt], acc[nt], 0, 0, 0);
  }
}

// ============ main: 64 edges/block, 4 waves, 16 edges/wave ============
// waves_per_eu(3) -> 170-VGPR budget: room for the pipelined B-batches and the
// fully-hoisted phase-1 gathers without spilling (R4/R5 lesson: watch WRITE_SIZE).
__global__ __attribute__((amdgpu_flat_work_group_size(256, 256), amdgpu_waves_per_eu(3)))
void bond_mlp_kernel(const int* __restrict__ bidx,
                     const float4* __restrict__ erec,
                     const uint16_t* __restrict__ Pa, const uint16_t* __restrict__ Pb,
                     const uint16_t* __restrict__ Tt, const uint16_t* __restrict__ w1f,
                     const uint16_t* __restrict__ w2f,
                     const float* __restrict__ b1, const float* __restrict__ ln1w,
                     const float* __restrict__ ln1b,
                     const float* __restrict__ b2, const float* __restrict__ ln2w,
                     const float* __restrict__ ln2b,
                     const float* __restrict__ Wo, const float* __restrict__ bo,
                     float* __restrict__ out) {
  __shared__ __align__(16) uint16_t hA_all[4 * 16 * 136];   // wave-private slices

  const int tid = threadIdx.x;
  const int lane = tid & 63;
  const int wave = tid >> 6;
  const int n15 = lane & 15;
  const int quad = lane >> 4;

  uint16_t* hA = hA_all + wave * (16 * 136);

  // ---- phase 1: h0 = lrelu(Pa[i]+Pb[j]+lerp(T,w)) -> hA; ALL 16 gathers hoisted ----
  {
    const int le = lane >> 2, sub = lane & 3;   // 4 lanes per edge
    const int ge = blockIdx.x * 64 + wave * 16 + le;
    const bool valid = ge < N_EDGES;
    int vi = 0, vj = 0;
    uint32_t pk = 0;
    if (valid) {
      int2 ij = *(const int2*)(bidx + 2 * ge);
      vi = ij.x; vj = ij.y;
      pk = __float_as_uint(erec[ge].w);
    }
    int row = pk & 0xFFFFu;
    float w = (float)(pk >> 16) * (1.0f / 65536.0f);
    f32x2 w2 = {w, w};
    // coalesced layout (R7): instr g's 4 edge-lanes read consecutive 16B of one line
    const uint4* pa = (const uint4*)(Pa + (size_t)vi * 128 + sub * 8);
    const uint4* pb = (const uint4*)(Pb + (size_t)vj * 128 + sub * 8);
    const uint16_t* trow = Tt + (size_t)row * 128 + sub * 8;
    const uint4* t0p = (const uint4*)trow;
    const uint4* t1p = (const uint4*)(trow + 128);
    uint4 AV[4], BV[4], T0[4], T1[4];
#pragma unroll
    for (int g = 0; g < 4; ++g) AV[g] = pa[g * 4];
#pragma unroll
    for (int g = 0; g < 4; ++g) BV[g] = pb[g * 4];
#pragma unroll
    for (int g = 0; g < 4; ++g) T0[g] = t0p[g * 4];
#pragma unroll
    for (int g = 0; g < 4; ++g) T1[g] = t1p[g * 4];
#pragma unroll
    for (int g = 0; g < 4; ++g) {
      uint4 opk;
      opk.x = comp2(AV[g].x, BV[g].x, T0[g].x, T1[g].x, w2);
      opk.y = comp2(AV[g].y, BV[g].y, T0[g].y, T1[g].y, w2);
      opk.z = comp2(AV[g].z, BV[g].z, T0[g].z, T1[g].z, w2);
      opk.w = comp2(AV[g].w, BV[g].w, T0[g].w, T1[g].w, w2);
      *(uint4*)(hA + le * 136 + g * 32 + sub * 8) = opk;   // matching permuted store
    }
  }
  // no barrier: hA is wave-private; compiler inserts lgkmcnt waits

  const uint16_t* aRow = hA + n15 * 136 + quad * 8;

  floatx4 acc[8];
#pragma unroll
  for (int nt = 0; nt < 8; ++nt) acc[nt] = (floatx4){0.f, 0.f, 0.f, 0.f};
  gemm_g(w1f, aRow, lane, acc);          // L1, pipelined B-loads

  // epilogue 1: +b1, LN, lrelu -> hA
  {
    float bv[8], wv[8], bb[8];
#pragma unroll
    for (int nt = 0; nt < 8; ++nt) {
      int col = nt * 16 + n15;
      bv[nt] = b1[col]; wv[nt] = ln1w[col]; bb[nt] = ln1b[col];
    }
    floatx4 s4 = {0.f, 0.f, 0.f, 0.f}, q4 = {0.f, 0.f, 0.f, 0.f};
#pragma unroll
    for (int nt = 0; nt < 8; ++nt) { floatx4 v = acc[nt] + bv[nt]; s4 += v; q4 += v * v; }
#pragma unroll
    for (int m = 1; m <= 8; m <<= 1) {
#pragma unroll
      for (int c = 0; c < 4; ++c) { s4[c] += __shfl_xor(s4[c], m); q4[c] += __shfl_xor(q4[c], m); }
    }
    floatx4 mean = s4 * (1.0f / 128.0f);
    floatx4 var = q4 * (1.0f / 128.0f) - mean * mean;
    floatx4 rstd;
    rstd.x = rsqrtf(var.x + 1e-5f); rstd.y = rsqrtf(var.y + 1e-5f);
    rstd.z = rsqrtf(var.z + 1e-5f); rstd.w = rsqrtf(var.w + 1e-5f);
#pragma unroll
    for (int nt = 0; nt < 8; ++nt) {
      floatx4 v = acc[nt] + bv[nt];
      floatx4 vn = lrelu4((v - mean) * (rstd * wv[nt]) + bb[nt]);
#pragma unroll
      for (int r = 0; r < 4; ++r)
        hA[(quad * 4 + r) * 136 + nt * 16 + n15] = bftrunc(vn[r]);
    }
  }
  // no barrier: hA is wave-private

#pragma unroll
  for (int nt = 0; nt < 8; ++nt) acc[nt] = (floatx4){0.f, 0.f, 0.f, 0.f};
  gemm_g(w2f, aRow, lane, acc);          // L2, pipelined B-loads

  // epilogue 2: +b2, LN, lrelu, force = h@Wo + bo, scatter atomics
  {
    float bv[8], wv[8], bb[8], wo0[8], wo1[8];
#pragma unroll
    for (int nt = 0; nt < 8; ++nt) {
      int col = nt * 16 + n15;
      bv[nt] = b2[col]; wv[nt] = ln2w[col]; bb[nt] = ln2b[col];
      wo0[nt] = Wo[2 * col]; wo1[nt] = Wo[2 * col + 1];
    }
    floatx4 s4 = {0.f, 0.f, 0.f, 0.f}, q4 = {0.f, 0.f, 0.f, 0.f};
#pragma unroll
    for (int nt = 0; nt < 8; ++nt) { floatx4 v = acc[nt] + bv[nt]; s4 += v; q4 += v * v; }
#pragma unroll
    for (int m = 1; m <= 8; m <<= 1) {
#pragma unroll
      for (int c = 0; c < 4; ++c) { s4[c] += __shfl_xor(s4[c], m); q4[c] += __shfl_xor(q4[c], m); }
    }
    floatx4 mean = s4 * (1.0f / 128.0f);
    floatx4 var = q4 * (1.0f / 128.0f) - mean * mean;
    floatx4 rstd;
    rstd.x = rsqrtf(var.x + 1e-5f); rstd.y = rsqrtf(var.y + 1e-5f);
    rstd.z = rsqrtf(var.z + 1e-5f); rstd.w = rsqrtf(var.w + 1e-5f);
    floatx4 f0 = {0.f, 0.f, 0.f, 0.f}, f1 = {0.f, 0.f, 0.f, 0.f};
#pragma unroll
    for (int nt = 0; nt < 8; ++nt) {
      floatx4 v = acc[nt] + bv[nt];
      floatx4 vn = lrelu4((v - mean) * (rstd * wv[nt]) + bb[nt]);
      f0 += vn * wo0[nt];
      f1 += vn * wo1[nt];
    }
#pragma unroll
    for (int m = 1; m <= 8; m <<= 1) {
#pragma unroll
      for (int c = 0; c < 4; ++c) { f0[c] += __shfl_xor(f0[c], m); f1[c] += __shfl_xor(f1[c], m); }
    }
    if (n15 < 4) {
      int ge2 = blockIdx.x * 64 + wave * 16 + quad * 4 + n15;
      if (ge2 < N_EDGES) {
        float F0 = (n15 == 0) ? f0.x : (n15 == 1) ? f0.y : (n15 == 2) ? f0.z : f0.w;
        float F1 = (n15 == 0) ? f1.x : (n15 == 1) ? f1.y : (n15 == 2) ? f1.z : f1.w;
        F0 += bo[0]; F1 += bo[1];
        float4 rec = erec[ge2];                       // coalesced: consecutive edges
        int2 ij = *(const int2*)(bidx + 2 * ge2);     // coalesced
        float c0 = 0.5f * F0;          // STEP * force0, along +u
        float c1 = -0.5f * F1;         // STEP * force1, along -u
        atomicAdd(out + 3 * ij.x,     c0 * rec.x);
        atomicAdd(out + 3 * ij.x + 1, c0 * rec.y);
        atomicAdd(out + 3 * ij.x + 2, c0 * rec.z);
        atomicAdd(out + 3 * ij.y,     c1 * rec.x);
        atomicAdd(out + 3 * ij.y + 1, c1 * rec.y);
        atomicAdd(out + 3 * ij.y + 2, c1 * rec.z);
      }
    }
  }
}

extern "C" void kernel_launch(void* const* d_in, const int* in_sizes, int n_in,
                              void* d_out, int out_size, void* d_ws, size_t ws_size,
                              hipStream_t stream) {
  const float* x    = (const float*)d_in[0];
  const float* pos  = (const float*)d_in[1];
  const float* nemb = (const float*)d_in[2];
  const int*   bidx = (const int*)d_in[3];
  const int*   btyp = (const int*)d_in[4];
  const float* bemb = (const float*)d_in[5];
  const float* W0   = (const float*)d_in[6];
  const float* b0   = (const float*)d_in[7];
  const float* W1   = (const float*)d_in[8];
  const float* b1   = (const float*)d_in[9];
  const float* ln1w = (const float*)d_in[10];
  const float* ln1b = (const float*)d_in[11];
  const float* W2   = (const float*)d_in[12];
  const float* b2   = (const float*)d_in[13];
  const float* ln2w = (const float*)d_in[14];
  const float* ln2b = (const float*)d_in[15];
  const float* Wo   = (const float*)d_in[16];
  const float* bo   = (const float*)d_in[17];
  float* out = (float*)d_out;

  // ws: frag weights 128KB + be0 2KB + T 1.31MB + Pa/Pb 51.2MB + erec 8MB
  uint16_t* w0ab = (uint16_t*)d_ws;                 // 32768 bf16
  uint16_t* w1f  = w0ab + 32768;                    // 16384
  uint16_t* w2f  = w1f + 16384;                     // 16384
  float*    be0f = (float*)(w2f + 16384);           // 512 f32
  uint16_t* Tt   = (uint16_t*)(be0f + 512);         // 4*TBINS*128 bf16
  uint16_t* Pa   = Tt + (size_t)4 * TBINS * 128;    // N_NODES*128 bf16
  uint16_t* Pb   = Pa + (size_t)N_NODES * 128;      // N_NODES*128 bf16
  float4*   erec = (float4*)(Pb + (size_t)N_NODES * 128);  // N_EDGES float4

  const int nblkP = (N_NODES + 64 * PREP_NG - 1) / (64 * PREP_NG);
  const int n0 = 66048 + out_size + N_EDGES;        // prep0 threads incl. edge records

  prep0_kernel<<<(n0 + 255) / 256, 256, 0, stream>>>(
      W0, b0, W1, W2, bemb, x, bidx, btyp,
      w0ab, w1f, w2f, be0f, erec, pos, out, out_size);
  prep_tp_kernel<<<TBINS + nblkP, 256, 0, stream>>>(
      W0, be0f, Tt, nemb, w0ab, Pa, Pb);
  bond_mlp_kernel<<<(N_EDGES + 63) / 64, 256, 0, stream>>>(
      bidx, erec, Pa, Pb, Tt, w1f, w2f,
      b1, ln1w, ln1b, b2, ln2w, ln2b, Wo, bo, out);
}